// Round 2
// baseline (12284.022 us; speedup 1.0000x reference)
//
#include <hip/hip_runtime.h>
#include <hip/hip_bf16.h>
#include <math.h>

// B=32, T=256, D=1024, A=64, H=512, NA=20
#define DEV __device__ __forceinline__

typedef __bf16 bf16_t;
typedef bf16_t bf16x8 __attribute__((ext_vector_type(8)));
typedef float f32x4 __attribute__((ext_vector_type(4)));

DEV void async16(const void* g, void* l) {
  __builtin_amdgcn_global_load_lds((const __attribute__((address_space(1))) void*)g,
                                   (__attribute__((address_space(3))) void*)l, 16, 0, 0);
}
DEV float sigmoidf_(float x) { return 1.f / (1.f + expf(-x)); }

// ---------------- generic bf16 MFMA GEMM: C[M,N] = A[M,K] @ Bw[N,K]^T + bias ----------------
// remap==1: output row m -> (m%256)*32 + m/256   (i.e. [B,T] -> [T,B])
// mode 0: outF = acc + bias (f32)
// mode 1: outBF = bf16(acc + bias)
// mode 2: outBF = bf16( sigmoid(acc+bias) * tanh(aux[row][n]) )   (leaf hid)
__global__ __launch_bounds__(256) void gemm_bt_kernel(
    const __hip_bfloat16* __restrict__ A, const __hip_bfloat16* __restrict__ Bw,
    float* __restrict__ outF, __hip_bfloat16* __restrict__ outBF,
    const float* __restrict__ bias, const float* __restrict__ aux,
    int M, int N, int K, int remap, int mode)
{
  __shared__ __hip_bfloat16 As[128 * 64];
  __shared__ __hip_bfloat16 Bs[128 * 64];
  const int tid = threadIdx.x;
  const int w = tid >> 6, l = tid & 63;
  const int m0 = blockIdx.x * 128, n0 = blockIdx.y * 128;
  const int wm = (w >> 1) * 64, wn = (w & 1) * 64;
  const int row_s = tid >> 3, kc = tid & 7;
  f32x4 acc[4][4] = {};
  for (int k0 = 0; k0 < K; k0 += 64) {
    const __hip_bfloat16* ga = A + (size_t)(m0 + row_s) * K + k0 + kc * 8;
    const __hip_bfloat16* gb = Bw + (size_t)(n0 + row_s) * K + k0 + kc * 8;
    __hip_bfloat16* la = As + w * 512;
    __hip_bfloat16* lb = Bs + w * 512;
#pragma unroll
    for (int p = 0; p < 4; ++p) {
      async16(ga + (size_t)p * 32 * K, la + p * 2048);
      async16(gb + (size_t)p * 32 * K, lb + p * 2048);
    }
    __syncthreads();
#pragma unroll
    for (int kb = 0; kb < 2; ++kb) {
      bf16x8 af[4], bfr[4];
#pragma unroll
      for (int i = 0; i < 4; ++i)
        af[i] = *(const bf16x8*)&As[(wm + i * 16 + (l & 15)) * 64 + kb * 32 + (l >> 4) * 8];
#pragma unroll
      for (int j = 0; j < 4; ++j)
        bfr[j] = *(const bf16x8*)&Bs[(wn + j * 16 + (l & 15)) * 64 + kb * 32 + (l >> 4) * 8];
#pragma unroll
      for (int i = 0; i < 4; ++i)
#pragma unroll
        for (int j = 0; j < 4; ++j)
          acc[i][j] = __builtin_amdgcn_mfma_f32_16x16x32_bf16(af[i], bfr[j], acc[i][j], 0, 0, 0);
    }
    __syncthreads();
  }
#pragma unroll
  for (int i = 0; i < 4; ++i) {
#pragma unroll
    for (int j = 0; j < 4; ++j) {
      const int ncol = n0 + wn + j * 16 + (l & 15);
      const float bv = bias ? bias[ncol] : 0.f;
#pragma unroll
      for (int r = 0; r < 4; ++r) {
        int m = m0 + wm + i * 16 + (l >> 4) * 4 + r;
        int row = remap ? (((m & 255) << 5) | (m >> 8)) : m;
        float v = acc[i][j][r] + bv;
        if (mode == 0) {
          outF[(size_t)row * N + ncol] = v;
        } else if (mode == 1) {
          outBF[(size_t)row * N + ncol] = __float2bfloat16(v);
        } else {
          float cv = aux[(size_t)row * N + ncol];
          outBF[(size_t)row * N + ncol] = __float2bfloat16(sigmoidf_(v) * tanhf(cv));
        }
      }
    }
  }
}

// ---------------- persistent scan ----------------
struct PP {
  const __hip_bfloat16* hid;     // [8192][1024]  rows t*32+b
  const float* cell;             // [8192][1024]  rows t*32+b
  const __hip_bfloat16 *Whh_s, *Wih_s, *Whh_r, *Whh_a;  // [4096][1024]
  const __hip_bfloat16 *xg_s, *xg_r;                    // [8192][4096] bias folded
  const float* table;            // [20][4096] f32
  const int* actions;            // [32][256]
  const float *stack_c0, *act_c0, *sbias;
  __hip_bfloat16 *sb0, *sb1, *rb0, *rb1, *ab0, *ab1;    // h dbuf [32][1024] bf16
  float *s1, *s2, *s3, *atop;    // [32][1024] f32
  unsigned int* ctr;             // [3]
};

DEV void mfma_pass_lds(const __hip_bfloat16* __restrict__ Ap, const __hip_bfloat16* Wl,
                       int mh, int nh, int l, f32x4& acc0, f32x4& acc1)
{
  const __hip_bfloat16* arow = Ap + (mh * 16 + (l & 15)) * 1024 + (l >> 4) * 8;
  const int sw = (l & 7) << 3;
  const int r0 = nh * 32 + (l & 15), r1 = r0 + 16;
#pragma unroll 8
  for (int kt = 0; kt < 32; ++kt) {
    const int k0 = kt * 32;
    const int kk = k0 + (l >> 4) * 8;
    bf16x8 a = *(const bf16x8*)&arow[k0];
    bf16x8 b0 = *(const bf16x8*)&Wl[r0 * 1024 + (kk ^ sw)];
    bf16x8 b1 = *(const bf16x8*)&Wl[r1 * 1024 + (kk ^ sw)];
    acc0 = __builtin_amdgcn_mfma_f32_16x16x32_bf16(a, b0, acc0, 0, 0, 0);
    acc1 = __builtin_amdgcn_mfma_f32_16x16x32_bf16(a, b1, acc1, 0, 0, 0);
  }
}

DEV void mfma_pass_glb(const __hip_bfloat16* __restrict__ Ap, const __hip_bfloat16* __restrict__ Wg,
                       int d0, int mh, int nh, int l, f32x4& acc0, f32x4& acc1)
{
  const __hip_bfloat16* arow = Ap + (mh * 16 + (l & 15)) * 1024 + (l >> 4) * 8;
  const size_t g0 = ((size_t)(2 * nh) * 1024 + d0 + (l & 15)) * 1024;
  const size_t g1 = g0 + 1024 * 1024;
#pragma unroll 4
  for (int kt = 0; kt < 32; ++kt) {
    const int k0 = kt * 32;
    const int kk = k0 + (l >> 4) * 8;
    bf16x8 a = *(const bf16x8*)&arow[k0];
    bf16x8 b0 = *(const bf16x8*)&Wg[g0 + kk];
    bf16x8 b1 = *(const bf16x8*)&Wg[g1 + kk];
    acc0 = __builtin_amdgcn_mfma_f32_16x16x32_bf16(a, b0, acc0, 0, 0, 0);
    acc1 = __builtin_amdgcn_mfma_f32_16x16x32_bf16(a, b1, acc1, 0, 0, 0);
  }
}

__global__ __launch_bounds__(256, 1) void scan_persist(PP P)
{
  __shared__ __hip_bfloat16 Wl[64 * 1024];   // 128 KB, XOR-swizzled
  __shared__ float gsm[32][16][4];           // 8 KB gate exchange
  const int bid = blockIdx.x;
  const int scan = bid >> 6;                 // 0 stack, 1 reduce, 2 action
  const int d0 = (bid & 63) * 16;
  const int tid = threadIdx.x;
  const int l = tid & 63, w = tid >> 6;
  const int mh = w >> 1, nh = w & 1;

  const __hip_bfloat16* Wg = (scan == 0) ? P.Whh_s : ((scan == 1) ? P.Whh_r : P.Whh_a);
  // stage W slice: local row r -> global row (r>>4)*1024 + d0 + (r&15); swizzle elem k ^= (r&7)<<3
  for (int idx = tid; idx < 64 * 128; idx += 256) {
    int r = idx >> 7, k = (idx & 127) * 8;
    int grow = ((r >> 4) << 10) + d0 + (r & 15);
    bf16x8 v = *(const bf16x8*)&Wg[(size_t)grow * 1024 + k];
    *(bf16x8*)&Wl[r * 1024 + (k ^ ((r & 7) << 3))] = v;
  }
  // persistent cell state in registers: thread owns (b,dd) pairs e and e+256
  const int e0 = tid, e1 = tid + 256;
  const int b0_ = e0 >> 4, dd0 = e0 & 15, b1_ = e1 >> 4, dd1 = e1 & 15;
  float creg0, creg1;
  if (scan == 0)      { creg0 = P.stack_c0[d0 + dd0]; creg1 = P.stack_c0[d0 + dd1]; }
  else if (scan == 1) { creg0 = P.cell[b0_ * 1024 + d0 + dd0]; creg1 = P.cell[b1_ * 1024 + d0 + dd1]; }
  else                { creg0 = P.act_c0[d0 + dd0]; creg1 = P.act_c0[d0 + dd1]; }
  __syncthreads();

  __hip_bfloat16 *bufA, *bufB;
  if (scan == 0)      { bufA = P.sb0; bufB = P.sb1; }
  else if (scan == 1) { bufA = P.rb0; bufB = P.rb1; }
  else                { bufA = P.ab0; bufB = P.ab1; }
  unsigned int* ctr = P.ctr + scan;
  const int Ns = (scan == 1) ? 255 : 256;
  const int mbase = mh * 16 + (l >> 4) * 4;

  for (int s = 0; s < Ns; ++s) {
    const __hip_bfloat16* Ap = (s & 1) ? bufB : bufA;
    if (scan == 1 && s == 0) Ap = P.hid;           // hid_t[0]
    __hip_bfloat16* Hout = (s & 1) ? bufA : bufB;
    f32x4 acc0 = {}, acc1 = {};
    mfma_pass_lds(Ap, Wl, mh, nh, l, acc0, acc1);
#pragma unroll
    for (int r = 0; r < 4; ++r) {
      gsm[mbase + r][l & 15][nh * 2 + 0] = acc0[r];
      gsm[mbase + r][l & 15][nh * 2 + 1] = acc1[r];
    }
    __syncthreads();
#pragma unroll
    for (int q = 0; q < 2; ++q) {
      const int b = q ? b1_ : b0_, dd = q ? dd1 : dd0;
      const int d = d0 + dd;
      float& creg = q ? creg1 : creg0;
      float g0 = gsm[b][dd][0], g1 = gsm[b][dd][1], g2 = gsm[b][dd][2], g3 = gsm[b][dd][3];
      if (scan == 1) {
        const __hip_bfloat16* xr = P.xg_r + ((size_t)(s + 1) * 32 + b) * 4096;
        float ig = sigmoidf_(g0 + __bfloat162float(xr[d]));
        float lg = sigmoidf_(g1 + __bfloat162float(xr[1024 + d]));
        float rg = sigmoidf_(g2 + __bfloat162float(xr[2048 + d]));
        float cand = tanhf(g3 + __bfloat162float(xr[3072 + d]));
        float rcv = P.cell[((size_t)(s + 1) * 32 + b) * 1024 + d];
        float c2 = ig * cand + lg * creg + rg * rcv;
        creg = c2;
        Hout[b * 1024 + d] = __float2bfloat16(tanhf(c2));
      } else {
        float bi0, bi1, bi2, bi3;
        if (scan == 0) {
          const __hip_bfloat16* xr = P.xg_s + ((size_t)s * 32 + b) * 4096;
          bi0 = __bfloat162float(xr[d]);        bi1 = __bfloat162float(xr[1024 + d]);
          bi2 = __bfloat162float(xr[2048 + d]); bi3 = __bfloat162float(xr[3072 + d]);
        } else {
          int a = P.actions[b * 256 + s];
          const float* tb = P.table + a * 4096;
          bi0 = tb[d]; bi1 = tb[1024 + d]; bi2 = tb[2048 + d]; bi3 = tb[3072 + d];
        }
        float c2 = sigmoidf_(g1 + bi1) * creg + sigmoidf_(g0 + bi0) * tanhf(g2 + bi2);
        float h2 = sigmoidf_(g3 + bi3) * tanhf(c2);
        creg = c2;
        Hout[b * 1024 + d] = __float2bfloat16(h2);
        if (scan == 0 && s == 254) P.s3[b * 1024 + d] = h2;
        if (scan == 0 && s == 255) P.s2[b * 1024 + d] = h2;
        if (scan == 2 && s == 255) P.atop[b * 1024 + d] = h2;
      }
    }
    __threadfence();
    __syncthreads();
    if (tid == 0) {
      __hip_atomic_fetch_add(ctr, 1u, __ATOMIC_RELEASE, __HIP_MEMORY_SCOPE_AGENT);
      const unsigned target = 64u * (unsigned)(s + 1);
      while (__hip_atomic_load(ctr, __ATOMIC_ACQUIRE, __HIP_MEMORY_SCOPE_AGENT) < target)
        __builtin_amdgcn_s_sleep(1);
    }
    __syncthreads();
    __threadfence();
  }

  if (scan == 0) {
    // wait for reduce scan, then s1 = lstm_cell(red_h, hf, cf)
    if (tid == 0) {
      while (__hip_atomic_load(P.ctr + 1, __ATOMIC_ACQUIRE, __HIP_MEMORY_SCOPE_AGENT) < 64u * 255u)
        __builtin_amdgcn_s_sleep(1);
    }
    __syncthreads();
    __threadfence();
    f32x4 acc0 = {}, acc1 = {};
    mfma_pass_lds(P.sb0, Wl, mh, nh, l, acc0, acc1);        // hf @ Whh^T
    mfma_pass_glb(P.rb1, P.Wih_s, d0, mh, nh, l, acc0, acc1);  // red_h @ Wih^T
#pragma unroll
    for (int r = 0; r < 4; ++r) {
      gsm[mbase + r][l & 15][nh * 2 + 0] = acc0[r];
      gsm[mbase + r][l & 15][nh * 2 + 1] = acc1[r];
    }
    __syncthreads();
#pragma unroll
    for (int q = 0; q < 2; ++q) {
      const int b = q ? b1_ : b0_, dd = q ? dd1 : dd0;
      const int d = d0 + dd;
      float creg = q ? creg1 : creg0;   // cf
      float g0 = gsm[b][dd][0], g1 = gsm[b][dd][1], g2 = gsm[b][dd][2], g3 = gsm[b][dd][3];
      float bi0 = P.sbias[d], bi1 = P.sbias[1024 + d], bi2 = P.sbias[2048 + d], bi3 = P.sbias[3072 + d];
      float c2 = sigmoidf_(g1 + bi1) * creg + sigmoidf_(g0 + bi0) * tanhf(g2 + bi2);
      float h2 = sigmoidf_(g3 + bi3) * tanhf(c2);
      P.s1[b * 1024 + d] = h2;
    }
  }
}

// ---------------- small utility kernels ----------------
__global__ void cast_kernel(__hip_bfloat16* dst, const float* src, int n) {
  int i = blockIdx.x * 256 + threadIdx.x;
  if (i < n) dst[i] = __float2bfloat16(src[i]);
}
__global__ void extract_half_kernel(__hip_bfloat16* dst, const float* src, int n,
                                    int src_stride, int src_off) {
  int i = blockIdx.x * 256 + threadIdx.x;   // n = 4096*1024
  if (i < n) {
    int r = i >> 10, k = i & 1023;
    dst[i] = __float2bfloat16(src[(size_t)r * src_stride + src_off + k]);
  }
}
__global__ void bias_kernel(float* dst, const float* a, const float* b, int n) {
  int i = blockIdx.x * 256 + threadIdx.x;
  if (i < n) dst[i] = a[i] + b[i];
}
__global__ void act_table_kernel(const float* emb, const float* Wih, const float* bih,
                                 const float* bhh, float* table) {
  int i = blockIdx.x * 256 + threadIdx.x;  // 20*4096
  int a = i >> 12, n = i & 4095;
  float acc = bih[n] + bhh[n];
  const float* er = emb + a * 64;
  const float* wr = Wih + (size_t)n * 64;
  for (int k = 0; k < 64; ++k) acc += er[k] * wr[k];
  table[i] = acc;
}
__global__ void init_states_kernel(const float* stack_h0, const float* act_h0,
                                   __hip_bfloat16* sb0, __hip_bfloat16* ab0,
                                   unsigned int* ctr)
{
  int i = blockIdx.x * 256 + threadIdx.x;  // 32768
  int d = i & 1023;
  sb0[i] = __float2bfloat16(stack_h0[d]);
  ab0[i] = __float2bfloat16(act_h0[d]);
  if (i < 4) ctr[i] = 0u;
}

// ---------------- attention ----------------
__global__ __launch_bounds__(256) void att_q_kernel(
    const float* s1, const float* s2, const float* s3, const float* attW, float* q)
{
  int eb = blockIdx.x, bg = blockIdx.y, j = blockIdx.z;
  const float* sj = (j == 0) ? s1 : ((j == 1) ? s2 : s3);
  __shared__ float ls[4][1024];
  int tid = threadIdx.x;
  for (int i = tid; i < 4096; i += 256)
    ls[i >> 10][i & 1023] = sj[(size_t)(bg * 4 + (i >> 10)) * 1024 + (i & 1023)];
  __syncthreads();
  int e = eb * 256 + tid;
  const float* Wj = attW + (size_t)j * 1024 * 1024;
  float a0 = 0, a1 = 0, a2 = 0, a3 = 0;
  for (int d = 0; d < 1024; ++d) {
    float wv = Wj[(size_t)d * 1024 + e];
    a0 += ls[0][d] * wv; a1 += ls[1][d] * wv; a2 += ls[2][d] * wv; a3 += ls[3][d] * wv;
  }
  q[((size_t)j * 32 + bg * 4 + 0) * 1024 + e] = a0;
  q[((size_t)j * 32 + bg * 4 + 1) * 1024 + e] = a1;
  q[((size_t)j * 32 + bg * 4 + 2) * 1024 + e] = a2;
  q[((size_t)j * 32 + bg * 4 + 3) * 1024 + e] = a3;
}

__global__ __launch_bounds__(256) void att_sc_kernel(const float* q, const float* sent, float* att)
{
  int b = blockIdx.x, j = blockIdx.y;
  __shared__ float qs[1024];
  __shared__ float wsm[256];
  __shared__ float red[8];
  int tid = threadIdx.x, w = tid >> 6, l = tid & 63;
  for (int i = tid; i < 1024; i += 256) qs[i] = q[((size_t)j * 32 + b) * 1024 + i];
  __syncthreads();
  const float* sp = sent + ((size_t)b * 256 + tid) * 1024;
  float dot = 0;
  for (int k = 0; k < 1024; ++k) dot += qs[k] * sp[k];
  float v = dot;
  for (int off = 32; off; off >>= 1) v = fmaxf(v, __shfl_xor(v, off));
  if (l == 0) red[w] = v;
  __syncthreads();
  float m = fmaxf(fmaxf(red[0], red[1]), fmaxf(red[2], red[3]));
  float ex = expf(dot - m);
  float sv = ex;
  for (int off = 32; off; off >>= 1) sv += __shfl_xor(sv, off);
  if (l == 0) red[4 + w] = sv;
  __syncthreads();
  float ssum = red[4] + red[5] + red[6] + red[7];
  wsm[tid] = ex / ssum;
  __syncthreads();
  for (int it = 0; it < 4; ++it) {
    int e = it * 256 + tid;
    float a = 0;
    for (int t2 = 0; t2 < 256; ++t2) a += wsm[t2] * sent[((size_t)b * 256 + t2) * 1024 + e];
    att[((size_t)j * 32 + b) * 1024 + e] = a;
  }
}

// ---------------- head ----------------
__global__ void feat_kernel(const float* s1, const float* s2, const float* s3,
                            const float* tok, const float* atop, const float* att, float* feat)
{
  int i = blockIdx.x * 256 + threadIdx.x;  // 32*8192
  int b = i >> 13, jj = (i >> 10) & 7, d = i & 1023;
  int sidx = b * 1024 + d;
  float v;
  switch (jj) {
    case 0: v = s1[sidx]; break;
    case 1: v = s2[sidx]; break;
    case 2: v = s3[sidx]; break;
    case 3: v = tok[d]; break;
    case 4: v = atop[sidx]; break;
    default: v = att[((size_t)(jj - 5) * 32 + b) * 1024 + d];
  }
  feat[i] = v;
}
__global__ __launch_bounds__(256) void head_kernel(const float* feat, const float* W,
                                                   const float* bias, float* fbuf)
{
  int i = blockIdx.x * 256 + threadIdx.x;  // 32*512
  int b = i >> 9, h = i & 511;
  const float* fr = feat + (size_t)b * 8192;
  const float* wr = W + (size_t)h * 8192;
  float a = bias[h];
  for (int k = 0; k < 8192; ++k) a += fr[k] * wr[k];
  fbuf[i] = tanhf(a);
}
__global__ void logits_kernel(const float* fbuf, const float* W, const float* bias, float* out)
{
  int b = blockIdx.x, tid = threadIdx.x;  // block 64
  __shared__ float lg[20];
  __shared__ float mred, lsred;
  if (tid < 20) {
    const float* fr = fbuf + b * 512;
    const float* wr = W + tid * 512;
    float a = bias[tid];
    for (int k = 0; k < 512; ++k) a += fr[k] * wr[k];
    lg[tid] = a;
  }
  __syncthreads();
  if (tid == 0) {
    float m = lg[0];
    for (int i = 1; i < 20; ++i) m = fmaxf(m, lg[i]);
    float ssum = 0;
    for (int i = 0; i < 20; ++i) ssum += expf(lg[i] - m);
    mred = m; lsred = logf(ssum);
  }
  __syncthreads();
  if (tid < 20) out[b * 20 + tid] = lg[tid] - mred - lsred;
}

// ---------------- host ----------------
extern "C" void kernel_launch(void* const* d_in, const int* in_sizes, int n_in,
                              void* d_out, int out_size, void* d_ws, size_t ws_size,
                              hipStream_t stream)
{
  const float* sentence = (const float*)d_in[0];
  const int* actions = (const int*)d_in[1];
  const float* token_empty = (const float*)d_in[2];
  const float* leaf_Wi = (const float*)d_in[3];
  const float* leaf_bi = (const float*)d_in[4];
  const float* leaf_Wo = (const float*)d_in[5];
  const float* leaf_bo = (const float*)d_in[6];
  const float* lstm_Wih = (const float*)d_in[7];
  const float* lstm_Whh = (const float*)d_in[8];
  const float* lstm_bih = (const float*)d_in[9];
  const float* lstm_bhh = (const float*)d_in[10];
  const float* stack_h0 = (const float*)d_in[11];
  const float* stack_c0 = (const float*)d_in[12];
  const float* act_emb = (const float*)d_in[13];
  const float* act_Wih = (const float*)d_in[14];
  const float* act_Whh = (const float*)d_in[15];
  const float* act_bih = (const float*)d_in[16];
  const float* act_bhh = (const float*)d_in[17];
  const float* act_h0 = (const float*)d_in[18];
  const float* act_c0 = (const float*)d_in[19];
  const float* red_W = (const float*)d_in[20];
  const float* red_b = (const float*)d_in[21];
  const float* h2f_W = (const float*)d_in[22];
  const float* h2f_b = (const float*)d_in[23];
  const float* f2a_W = (const float*)d_in[24];
  const float* f2a_b = (const float*)d_in[25];
  const float* att_W = (const float*)d_in[26];
  float* out = (float*)d_out;
  (void)in_sizes; (void)n_in; (void)out_size; (void)ws_size;

  char* ws = (char*)d_ws;
  size_t off = 0;
  auto alloc = [&](size_t bytes) -> void* {
    void* ptr = ws + off;
    off += (bytes + 255) & ~(size_t)255;
    return ptr;
  };
  __hip_bfloat16* sent_bf = (__hip_bfloat16*)alloc(16777216);   // [8192][1024] (b*256+t)
  __hip_bfloat16* hid_bf  = (__hip_bfloat16*)alloc(16777216);   // [8192][1024] (t*32+b)
  float* cell_f32 = (float*)alloc(33554432);                    // [8192][1024] (t*32+b)
  __hip_bfloat16* lWi_bf = (__hip_bfloat16*)alloc(2097152);
  __hip_bfloat16* lWo_bf = (__hip_bfloat16*)alloc(2097152);
  __hip_bfloat16* Whh_s = (__hip_bfloat16*)alloc(8388608);
  __hip_bfloat16* Wih_s = (__hip_bfloat16*)alloc(8388608);
  __hip_bfloat16* Whh_r = (__hip_bfloat16*)alloc(8388608);
  __hip_bfloat16* Wx_r  = (__hip_bfloat16*)alloc(8388608);
  __hip_bfloat16* Whh_a = (__hip_bfloat16*)alloc(8388608);
  __hip_bfloat16* xg_s = (__hip_bfloat16*)alloc(67108864);      // [8192][4096]
  __hip_bfloat16* xg_r = (__hip_bfloat16*)alloc(67108864);
  float* table = (float*)alloc(327680);
  float* sbias = (float*)alloc(16384);
  __hip_bfloat16* sb0 = (__hip_bfloat16*)alloc(65536);
  __hip_bfloat16* sb1 = (__hip_bfloat16*)alloc(65536);
  __hip_bfloat16* rb0 = (__hip_bfloat16*)alloc(65536);
  __hip_bfloat16* rb1 = (__hip_bfloat16*)alloc(65536);
  __hip_bfloat16* ab0 = (__hip_bfloat16*)alloc(65536);
  __hip_bfloat16* ab1 = (__hip_bfloat16*)alloc(65536);
  float* s1 = (float*)alloc(131072);
  float* s2 = (float*)alloc(131072);
  float* s3 = (float*)alloc(131072);
  float* atop = (float*)alloc(131072);
  unsigned int* ctrs = (unsigned int*)alloc(256);
  float* qbuf = (float*)alloc(393216);
  float* attbuf = (float*)alloc(393216);
  float* feat = (float*)alloc(1048576);
  float* fbuf = (float*)alloc(65536);

  // conversions
  cast_kernel<<<32768, 256, 0, stream>>>(sent_bf, sentence, 8388608);
  cast_kernel<<<4096, 256, 0, stream>>>(lWi_bf, leaf_Wi, 1048576);
  cast_kernel<<<4096, 256, 0, stream>>>(lWo_bf, leaf_Wo, 1048576);
  cast_kernel<<<16384, 256, 0, stream>>>(Whh_s, lstm_Whh, 4194304);
  cast_kernel<<<16384, 256, 0, stream>>>(Wih_s, lstm_Wih, 4194304);
  cast_kernel<<<16384, 256, 0, stream>>>(Whh_a, act_Whh, 4194304);
  extract_half_kernel<<<16384, 256, 0, stream>>>(Whh_r, red_W, 4194304, 2048, 0);
  extract_half_kernel<<<16384, 256, 0, stream>>>(Wx_r, red_W, 4194304, 2048, 1024);
  bias_kernel<<<16, 256, 0, stream>>>(sbias, lstm_bih, lstm_bhh, 4096);
  act_table_kernel<<<320, 256, 0, stream>>>(act_emb, act_Wih, act_bih, act_bhh, table);

  // leaf module: cell = sent@Wi^T + bi ; hid = sigmoid(sent@Wo^T+bo)*tanh(cell)
  gemm_bt_kernel<<<dim3(64, 8), 256, 0, stream>>>(sent_bf, lWi_bf, cell_f32, nullptr,
                                                  leaf_bi, nullptr, 8192, 1024, 1024, 1, 0);
  gemm_bt_kernel<<<dim3(64, 8), 256, 0, stream>>>(sent_bf, lWo_bf, nullptr, hid_bf,
                                                  leaf_bo, cell_f32, 8192, 1024, 1024, 1, 2);

  // precomputed x-gates (bias folded): xg_s = hid@lstm_Wih^T + sbias ; xg_r = hid@Wx_r^T + red_b
  gemm_bt_kernel<<<dim3(64, 32), 256, 0, stream>>>(hid_bf, Wih_s, nullptr, xg_s,
                                                   sbias, nullptr, 8192, 4096, 1024, 0, 1);
  gemm_bt_kernel<<<dim3(64, 32), 256, 0, stream>>>(hid_bf, Wx_r, nullptr, xg_r,
                                                   red_b, nullptr, 8192, 4096, 1024, 0, 1);

  init_states_kernel<<<128, 256, 0, stream>>>(stack_h0, act_h0, sb0, ab0, ctrs);

  PP P;
  P.hid = hid_bf; P.cell = cell_f32;
  P.Whh_s = Whh_s; P.Wih_s = Wih_s; P.Whh_r = Whh_r; P.Whh_a = Whh_a;
  P.xg_s = xg_s; P.xg_r = xg_r;
  P.table = table; P.actions = actions;
  P.stack_c0 = stack_c0; P.act_c0 = act_c0; P.sbias = sbias;
  P.sb0 = sb0; P.sb1 = sb1; P.rb0 = rb0; P.rb1 = rb1; P.ab0 = ab0; P.ab1 = ab1;
  P.s1 = s1; P.s2 = s2; P.s3 = s3; P.atop = atop;
  P.ctr = ctrs;
  scan_persist<<<192, 256, 0, stream>>>(P);

  // attention: s1, s2, s3
  att_q_kernel<<<dim3(4, 8, 3), 256, 0, stream>>>(s1, s2, s3, att_W, qbuf);
  att_sc_kernel<<<dim3(32, 3), 256, 0, stream>>>(qbuf, sentence, attbuf);

  // head
  feat_kernel<<<1024, 256, 0, stream>>>(s1, s2, s3, token_empty, atop, attbuf, feat);
  head_kernel<<<64, 256, 0, stream>>>(feat, h2f_W, h2f_b, fbuf);
  logits_kernel<<<32, 64, 0, stream>>>(fbuf, f2a_W, f2a_b, out);
}

// Round 3
// 3458.038 us; speedup vs baseline: 3.5523x; 3.5523x over previous
//
#include <hip/hip_runtime.h>
#include <hip/hip_bf16.h>
#include <math.h>

// B=32, T=256, D=1024, A=64, H=512, NA=20
#define DEV __device__ __forceinline__

typedef __bf16 bf16_t;
typedef bf16_t bf16x8 __attribute__((ext_vector_type(8)));
typedef float f32x4 __attribute__((ext_vector_type(4)));
typedef int i32x4 __attribute__((ext_vector_type(4)));

DEV void async16(const void* g, void* l) {
  __builtin_amdgcn_global_load_lds((const __attribute__((address_space(1))) void*)g,
                                   (__attribute__((address_space(3))) void*)l, 16, 0, 0);
}
DEV float sigmoidf_(float x) { return 1.f / (1.f + expf(-x)); }
DEV bf16x8 as_bf(i32x4 v) { union { i32x4 i; bf16x8 b; } u; u.i = v; return u.b; }

// ---- fine-grained device-coherent ops (bypass L1+L2, hit Infinity Cache) ----
DEV void flag_store(unsigned* p, unsigned v) {
  asm volatile("global_store_dword %0, %1, off sc0 sc1" :: "v"(p), "v"(v) : "memory");
}
DEV unsigned flag_load(const unsigned* p) {
  unsigned v;
  asm volatile("global_load_dword %0, %1, off sc0 sc1\ns_waitcnt vmcnt(0)"
               : "=v"(v) : "v"(p) : "memory");
  return v;
}
DEV void store_bf16_sys(__hip_bfloat16* p, float f) {
  union { __hip_bfloat16 b; unsigned short u; } cv;
  cv.b = __float2bfloat16(f);
  unsigned v = cv.u;
  asm volatile("global_store_short %0, %1, off sc0 sc1" :: "v"(p), "v"(v) : "memory");
}

#define WAITV(N) do { asm volatile("s_waitcnt vmcnt(" #N ")" ::: "memory"); \
                      __builtin_amdgcn_sched_barrier(0); } while (0)

template<int KB>
DEV void loads8(i32x4* dst, const __hip_bfloat16* arow) {
#pragma unroll
  for (int i = 0; i < 8; ++i)
    asm volatile("global_load_dwordx4 %0, %1, off offset:%2 sc0 sc1"
                 : "=v"(dst[i]) : "v"(arow), "i"((KB + i) * 64));
}
DEV void loads8rt(i32x4* dst, const __hip_bfloat16* arow, int kbase) {
#pragma unroll
  for (int i = 0; i < 8; ++i)
    asm volatile("global_load_dwordx4 %0, %1, off sc0 sc1"
                 : "=v"(dst[i]) : "v"(arow + (size_t)(kbase + i) * 32) : "memory");
}

template<int C>
DEV void ldsb8(bf16x8* b0, bf16x8* b1, const __hip_bfloat16* Wl,
               int sw, int kof, int r0, int r1) {
#pragma unroll
  for (int i = 0; i < 8; ++i) {
    const int kk = (C * 8 + i) * 32 + kof;
    b0[i] = *(const bf16x8*)&Wl[r0 * 1024 + (kk ^ sw)];
    b1[i] = *(const bf16x8*)&Wl[r1 * 1024 + (kk ^ sw)];
  }
}
DEV void mfma8x(const i32x4* a, const bf16x8* b0, const bf16x8* b1,
                f32x4& acc0, f32x4& acc1) {
#pragma unroll
  for (int i = 0; i < 8; ++i) {
    bf16x8 av = as_bf(a[i]);
    acc0 = __builtin_amdgcn_mfma_f32_16x16x32_bf16(av, b0[i], acc0, 0, 0, 0);
    acc1 = __builtin_amdgcn_mfma_f32_16x16x32_bf16(av, b1[i], acc1, 0, 0, 0);
  }
}

// K=1024 recurrent GEMM: A (h-state, bypass loads) x W (LDS-resident), 2-deep pipeline
DEV void mfma_step(const __hip_bfloat16* Ap, const __hip_bfloat16* Wl,
                   int mh, int nh, int l, f32x4& acc0, f32x4& acc1) {
  const __hip_bfloat16* arow = Ap + (mh * 16 + (l & 15)) * 1024 + (l >> 4) * 8;
  const int sw = (l & 7) << 3, kof = (l >> 4) * 8;
  const int r0 = nh * 32 + (l & 15), r1 = r0 + 16;
  i32x4 A0[8], A1[8];
  bf16x8 Ba0[8], Ba1[8], Bb0[8], Bb1[8];
  loads8<0>(A0, arow);
  loads8<8>(A1, arow);
  ldsb8<0>(Ba0, Ba1, Wl, sw, kof, r0, r1);
  WAITV(8);
  mfma8x(A0, Ba0, Ba1, acc0, acc1);
  loads8<16>(A0, arow);
  ldsb8<1>(Bb0, Bb1, Wl, sw, kof, r0, r1);
  WAITV(8);
  mfma8x(A1, Bb0, Bb1, acc0, acc1);
  loads8<24>(A1, arow);
  ldsb8<2>(Ba0, Ba1, Wl, sw, kof, r0, r1);
  WAITV(8);
  mfma8x(A0, Ba0, Ba1, acc0, acc1);
  ldsb8<3>(Bb0, Bb1, Wl, sw, kof, r0, r1);
  WAITV(0);
  mfma8x(A1, Bb0, Bb1, acc0, acc1);
}

// final-phase pass: A bypass loads, W from global (cached)
DEV void mfma_pass_glb(const __hip_bfloat16* Ap, const __hip_bfloat16* __restrict__ Wg,
                       int d0, int mh, int nh, int l, f32x4& acc0, f32x4& acc1) {
  const __hip_bfloat16* arow = Ap + (mh * 16 + (l & 15)) * 1024 + (l >> 4) * 8;
  const size_t g0 = ((size_t)(2 * nh) * 1024 + d0 + (l & 15)) * 1024;
  const size_t g1 = g0 + 1048576;
  const int kof = (l >> 4) * 8;
  i32x4 A[8];
  for (int c = 0; c < 4; ++c) {
    loads8rt(A, arow, c * 8);
    WAITV(0);
#pragma unroll
    for (int i = 0; i < 8; ++i) {
      const int kk = (c * 8 + i) * 32 + kof;
      bf16x8 b0 = *(const bf16x8*)&Wg[g0 + kk];
      bf16x8 b1 = *(const bf16x8*)&Wg[g1 + kk];
      bf16x8 av = as_bf(A[i]);
      acc0 = __builtin_amdgcn_mfma_f32_16x16x32_bf16(av, b0, acc0, 0, 0, 0);
      acc1 = __builtin_amdgcn_mfma_f32_16x16x32_bf16(av, b1, acc1, 0, 0, 0);
    }
  }
}

// ---------------- generic bf16 MFMA GEMM: C[M,N] = A[M,K] @ Bw[N,K]^T + bias ----------------
__global__ __launch_bounds__(256) void gemm_bt_kernel(
    const __hip_bfloat16* __restrict__ A, const __hip_bfloat16* __restrict__ Bw,
    float* __restrict__ outF, __hip_bfloat16* __restrict__ outBF,
    const float* __restrict__ bias, const float* __restrict__ aux,
    int M, int N, int K, int remap, int mode)
{
  __shared__ __hip_bfloat16 As[128 * 64];
  __shared__ __hip_bfloat16 Bs[128 * 64];
  const int tid = threadIdx.x;
  const int w = tid >> 6, l = tid & 63;
  const int m0 = blockIdx.x * 128, n0 = blockIdx.y * 128;
  const int wm = (w >> 1) * 64, wn = (w & 1) * 64;
  const int row_s = tid >> 3, kc = tid & 7;
  f32x4 acc[4][4] = {};
  for (int k0 = 0; k0 < K; k0 += 64) {
    const __hip_bfloat16* ga = A + (size_t)(m0 + row_s) * K + k0 + kc * 8;
    const __hip_bfloat16* gb = Bw + (size_t)(n0 + row_s) * K + k0 + kc * 8;
    __hip_bfloat16* la = As + w * 512;
    __hip_bfloat16* lb = Bs + w * 512;
#pragma unroll
    for (int p = 0; p < 4; ++p) {
      async16(ga + (size_t)p * 32 * K, la + p * 2048);
      async16(gb + (size_t)p * 32 * K, lb + p * 2048);
    }
    __syncthreads();
#pragma unroll
    for (int kb = 0; kb < 2; ++kb) {
      bf16x8 af[4], bfr[4];
#pragma unroll
      for (int i = 0; i < 4; ++i)
        af[i] = *(const bf16x8*)&As[(wm + i * 16 + (l & 15)) * 64 + kb * 32 + (l >> 4) * 8];
#pragma unroll
      for (int j = 0; j < 4; ++j)
        bfr[j] = *(const bf16x8*)&Bs[(wn + j * 16 + (l & 15)) * 64 + kb * 32 + (l >> 4) * 8];
#pragma unroll
      for (int i = 0; i < 4; ++i)
#pragma unroll
        for (int j = 0; j < 4; ++j)
          acc[i][j] = __builtin_amdgcn_mfma_f32_16x16x32_bf16(af[i], bfr[j], acc[i][j], 0, 0, 0);
    }
    __syncthreads();
  }
#pragma unroll
  for (int i = 0; i < 4; ++i) {
#pragma unroll
    for (int j = 0; j < 4; ++j) {
      const int ncol = n0 + wn + j * 16 + (l & 15);
      const float bv = bias ? bias[ncol] : 0.f;
#pragma unroll
      for (int r = 0; r < 4; ++r) {
        int m = m0 + wm + i * 16 + (l >> 4) * 4 + r;
        int row = remap ? (((m & 255) << 5) | (m >> 8)) : m;
        float v = acc[i][j][r] + bv;
        if (mode == 0) {
          outF[(size_t)row * N + ncol] = v;
        } else if (mode == 1) {
          outBF[(size_t)row * N + ncol] = __float2bfloat16(v);
        } else {
          float cv = aux[(size_t)row * N + ncol];
          outBF[(size_t)row * N + ncol] = __float2bfloat16(sigmoidf_(v) * tanhf(cv));
        }
      }
    }
  }
}

// ---------------- persistent scan ----------------
struct PP {
  const __hip_bfloat16* hid;     // [8192][1024]  rows t*32+b
  const float* cell;             // [8192][1024]  rows t*32+b
  const __hip_bfloat16 *Whh_s, *Wih_s, *Whh_r, *Whh_a;  // [4096][1024]
  const __hip_bfloat16 *xg_s, *xg_r;                    // [8192][4096] bias folded
  const float* table;            // [20][4096]
  const int* actions;            // [32][256]
  const float *stack_c0, *act_c0, *sbias;
  __hip_bfloat16 *sb0, *sb1, *rb0, *rb1, *ab0, *ab1;    // h dbuf [32][1024] bf16
  float *s1, *s2, *s3, *atop;    // [32][1024] f32
  unsigned int* flags;           // [3*64]
};

__global__ __launch_bounds__(256, 1) void scan_persist(PP P)
{
  __shared__ __hip_bfloat16 Wl[64 * 1024];   // 128 KB, XOR-swizzled
  __shared__ float gsm[32][16][4];           // 8 KB gate exchange
  const int bid = blockIdx.x;
  const int scan = bid >> 6;                 // 0 stack, 1 reduce, 2 action
  const int slot = bid & 63;
  const int d0 = slot * 16;
  const int tid = threadIdx.x;
  const int l = tid & 63, w = tid >> 6;
  const int mh = w >> 1, nh = w & 1;

  const __hip_bfloat16* Wg = (scan == 0) ? P.Whh_s : ((scan == 1) ? P.Whh_r : P.Whh_a);
  // stage W slice: local row r <- global row (r>>4)*1024 + d0 + (r&15); swizzle k ^= (r&7)<<3
  for (int idx = tid; idx < 64 * 128; idx += 256) {
    int r = idx >> 7, k = (idx & 127) * 8;
    int grow = ((r >> 4) << 10) + d0 + (r & 15);
    bf16x8 v = *(const bf16x8*)&Wg[(size_t)grow * 1024 + k];
    *(bf16x8*)&Wl[r * 1024 + (k ^ ((r & 7) << 3))] = v;
  }
  // persistent cell state in registers: thread owns (b,dd) pairs e and e+256
  const int e0 = tid, e1 = tid + 256;
  const int b0_ = e0 >> 4, dd0 = e0 & 15, b1_ = e1 >> 4, dd1 = e1 & 15;
  float creg0, creg1;
  if (scan == 0)      { creg0 = P.stack_c0[d0 + dd0]; creg1 = P.stack_c0[d0 + dd1]; }
  else if (scan == 1) { creg0 = P.cell[b0_ * 1024 + d0 + dd0]; creg1 = P.cell[b1_ * 1024 + d0 + dd1]; }
  else                { creg0 = P.act_c0[d0 + dd0]; creg1 = P.act_c0[d0 + dd1]; }
  __syncthreads();

  __hip_bfloat16 *bufA, *bufB;
  if (scan == 0)      { bufA = P.sb0; bufB = P.sb1; }
  else if (scan == 1) { bufA = P.rb0; bufB = P.rb1; }
  else                { bufA = P.ab0; bufB = P.ab1; }
  unsigned int* Fb = P.flags + scan * 64;
  const int Ns = (scan == 1) ? 255 : 256;
  const int mbase = mh * 16 + (l >> 4) * 4;

  for (int s = 0; s < Ns; ++s) {
    const __hip_bfloat16* Ap = (s & 1) ? bufB : bufA;
    if (scan == 1 && s == 0) Ap = P.hid;           // hid_t[0]
    __hip_bfloat16* Hout = (s & 1) ? bufA : bufB;
    f32x4 acc0 = {}, acc1 = {};
    mfma_step(Ap, Wl, mh, nh, l, acc0, acc1);
#pragma unroll
    for (int r = 0; r < 4; ++r) {
      gsm[mbase + r][l & 15][nh * 2 + 0] = acc0[r];
      gsm[mbase + r][l & 15][nh * 2 + 1] = acc1[r];
    }
    __syncthreads();
#pragma unroll
    for (int q = 0; q < 2; ++q) {
      const int b = q ? b1_ : b0_, dd = q ? dd1 : dd0;
      const int d = d0 + dd;
      float& creg = q ? creg1 : creg0;
      float g0 = gsm[b][dd][0], g1 = gsm[b][dd][1], g2 = gsm[b][dd][2], g3 = gsm[b][dd][3];
      if (scan == 1) {
        const __hip_bfloat16* xr = P.xg_r + ((size_t)(s + 1) * 32 + b) * 4096;
        float ig = sigmoidf_(g0 + __bfloat162float(xr[d]));
        float lg = sigmoidf_(g1 + __bfloat162float(xr[1024 + d]));
        float rg = sigmoidf_(g2 + __bfloat162float(xr[2048 + d]));
        float cand = tanhf(g3 + __bfloat162float(xr[3072 + d]));
        float rcv = P.cell[((size_t)(s + 1) * 32 + b) * 1024 + d];
        float c2 = ig * cand + lg * creg + rg * rcv;
        creg = c2;
        store_bf16_sys(Hout + b * 1024 + d, tanhf(c2));
      } else {
        float bi0, bi1, bi2, bi3;
        if (scan == 0) {
          const __hip_bfloat16* xr = P.xg_s + ((size_t)s * 32 + b) * 4096;
          bi0 = __bfloat162float(xr[d]);        bi1 = __bfloat162float(xr[1024 + d]);
          bi2 = __bfloat162float(xr[2048 + d]); bi3 = __bfloat162float(xr[3072 + d]);
        } else {
          int a = P.actions[b * 256 + s];
          const float* tb = P.table + a * 4096;
          bi0 = tb[d]; bi1 = tb[1024 + d]; bi2 = tb[2048 + d]; bi3 = tb[3072 + d];
        }
        float c2 = sigmoidf_(g1 + bi1) * creg + sigmoidf_(g0 + bi0) * tanhf(g2 + bi2);
        float h2 = sigmoidf_(g3 + bi3) * tanhf(c2);
        creg = c2;
        store_bf16_sys(Hout + b * 1024 + d, h2);
        if (scan == 0 && s == 254) P.s3[b * 1024 + d] = h2;
        if (scan == 0 && s == 255) P.s2[b * 1024 + d] = h2;
        if (scan == 2 && s == 255) P.atop[b * 1024 + d] = h2;
      }
    }
    // ---- lightweight device barrier: flags (no cache maintenance) ----
    asm volatile("s_waitcnt vmcnt(0)" ::: "memory");
    __syncthreads();
    if (tid == 0) flag_store(Fb + slot, (unsigned)(s + 1));
    if (tid < 64) {
      const unsigned tgt = (unsigned)(s + 1);
      while (flag_load(Fb + tid) < tgt) __builtin_amdgcn_s_sleep(2);
    }
    __syncthreads();
  }

  if (scan == 0) {
    // wait for reduce scan, then s1 = lstm_cell(red_h, hf, cf)
    if (tid < 64) {
      while (flag_load(P.flags + 64 + tid) < 255u) __builtin_amdgcn_s_sleep(2);
    }
    __syncthreads();
    f32x4 acc0 = {}, acc1 = {};
    mfma_step(P.sb0, Wl, mh, nh, l, acc0, acc1);              // hf @ Whh^T (bypass A)
    mfma_pass_glb(P.rb1, P.Wih_s, d0, mh, nh, l, acc0, acc1); // red_h @ Wih^T
#pragma unroll
    for (int r = 0; r < 4; ++r) {
      gsm[mbase + r][l & 15][nh * 2 + 0] = acc0[r];
      gsm[mbase + r][l & 15][nh * 2 + 1] = acc1[r];
    }
    __syncthreads();
#pragma unroll
    for (int q = 0; q < 2; ++q) {
      const int b = q ? b1_ : b0_, dd = q ? dd1 : dd0;
      const int d = d0 + dd;
      float creg = q ? creg1 : creg0;   // cf
      float g0 = gsm[b][dd][0], g1 = gsm[b][dd][1], g2 = gsm[b][dd][2], g3 = gsm[b][dd][3];
      float bi0 = P.sbias[d], bi1 = P.sbias[1024 + d], bi2 = P.sbias[2048 + d], bi3 = P.sbias[3072 + d];
      float c2 = sigmoidf_(g1 + bi1) * creg + sigmoidf_(g0 + bi0) * tanhf(g2 + bi2);
      float h2 = sigmoidf_(g3 + bi3) * tanhf(c2);
      P.s1[b * 1024 + d] = h2;
    }
  }
}

// ---------------- small utility kernels ----------------
__global__ void cast_kernel(__hip_bfloat16* dst, const float* src, int n) {
  int i = blockIdx.x * 256 + threadIdx.x;
  if (i < n) dst[i] = __float2bfloat16(src[i]);
}
__global__ void extract_half_kernel(__hip_bfloat16* dst, const float* src, int n,
                                    int src_stride, int src_off) {
  int i = blockIdx.x * 256 + threadIdx.x;   // n = 4096*1024
  if (i < n) {
    int r = i >> 10, k = i & 1023;
    dst[i] = __float2bfloat16(src[(size_t)r * src_stride + src_off + k]);
  }
}
__global__ void bias_kernel(float* dst, const float* a, const float* b, int n) {
  int i = blockIdx.x * 256 + threadIdx.x;
  if (i < n) dst[i] = a[i] + b[i];
}
__global__ void act_table_kernel(const float* emb, const float* Wih, const float* bih,
                                 const float* bhh, float* table) {
  int i = blockIdx.x * 256 + threadIdx.x;  // 20*4096
  int a = i >> 12, n = i & 4095;
  float acc = bih[n] + bhh[n];
  const float* er = emb + a * 64;
  const float* wr = Wih + (size_t)n * 64;
  for (int k = 0; k < 64; ++k) acc += er[k] * wr[k];
  table[i] = acc;
}
__global__ void init_states_kernel(const float* stack_h0, const float* act_h0,
                                   __hip_bfloat16* sb0, __hip_bfloat16* ab0,
                                   unsigned int* flags)
{
  int i = blockIdx.x * 256 + threadIdx.x;  // 32768
  int d = i & 1023;
  sb0[i] = __float2bfloat16(stack_h0[d]);
  ab0[i] = __float2bfloat16(act_h0[d]);
  if (i < 192) flags[i] = 0u;
}

// ---------------- attention ----------------
__global__ __launch_bounds__(256) void att_q_kernel(
    const float* s1, const float* s2, const float* s3, const float* attW, float* q)
{
  int eb = blockIdx.x, bg = blockIdx.y, j = blockIdx.z;
  const float* sj = (j == 0) ? s1 : ((j == 1) ? s2 : s3);
  __shared__ float ls[4][1024];
  int tid = threadIdx.x;
  for (int i = tid; i < 4096; i += 256)
    ls[i >> 10][i & 1023] = sj[(size_t)(bg * 4 + (i >> 10)) * 1024 + (i & 1023)];
  __syncthreads();
  int e = eb * 256 + tid;
  const float* Wj = attW + (size_t)j * 1024 * 1024;
  float a0 = 0, a1 = 0, a2 = 0, a3 = 0;
  for (int d = 0; d < 1024; ++d) {
    float wv = Wj[(size_t)d * 1024 + e];
    a0 += ls[0][d] * wv; a1 += ls[1][d] * wv; a2 += ls[2][d] * wv; a3 += ls[3][d] * wv;
  }
  q[((size_t)j * 32 + bg * 4 + 0) * 1024 + e] = a0;
  q[((size_t)j * 32 + bg * 4 + 1) * 1024 + e] = a1;
  q[((size_t)j * 32 + bg * 4 + 2) * 1024 + e] = a2;
  q[((size_t)j * 32 + bg * 4 + 3) * 1024 + e] = a3;
}

__global__ __launch_bounds__(256) void att_sc_kernel(const float* q, const float* sent, float* att)
{
  int b = blockIdx.x, j = blockIdx.y;
  __shared__ float qs[1024];
  __shared__ float wsm[256];
  __shared__ float red[8];
  int tid = threadIdx.x, w = tid >> 6, l = tid & 63;
  for (int i = tid; i < 1024; i += 256) qs[i] = q[((size_t)j * 32 + b) * 1024 + i];
  __syncthreads();
  const float* sp = sent + ((size_t)b * 256 + tid) * 1024;
  float dot = 0;
  for (int k = 0; k < 1024; ++k) dot += qs[k] * sp[k];
  float v = dot;
  for (int off = 32; off; off >>= 1) v = fmaxf(v, __shfl_xor(v, off));
  if (l == 0) red[w] = v;
  __syncthreads();
  float m = fmaxf(fmaxf(red[0], red[1]), fmaxf(red[2], red[3]));
  float ex = expf(dot - m);
  float sv = ex;
  for (int off = 32; off; off >>= 1) sv += __shfl_xor(sv, off);
  if (l == 0) red[4 + w] = sv;
  __syncthreads();
  float ssum = red[4] + red[5] + red[6] + red[7];
  wsm[tid] = ex / ssum;
  __syncthreads();
  for (int it = 0; it < 4; ++it) {
    int e = it * 256 + tid;
    float a = 0;
    for (int t2 = 0; t2 < 256; ++t2) a += wsm[t2] * sent[((size_t)b * 256 + t2) * 1024 + e];
    att[((size_t)j * 32 + b) * 1024 + e] = a;
  }
}

// ---------------- head ----------------
__global__ void feat_kernel(const float* s1, const float* s2, const float* s3,
                            const float* tok, const float* atop, const float* att, float* feat)
{
  int i = blockIdx.x * 256 + threadIdx.x;  // 32*8192
  int b = i >> 13, jj = (i >> 10) & 7, d = i & 1023;
  int sidx = b * 1024 + d;
  float v;
  switch (jj) {
    case 0: v = s1[sidx]; break;
    case 1: v = s2[sidx]; break;
    case 2: v = s3[sidx]; break;
    case 3: v = tok[d]; break;
    case 4: v = atop[sidx]; break;
    default: v = att[((size_t)(jj - 5) * 32 + b) * 1024 + d];
  }
  feat[i] = v;
}
__global__ __launch_bounds__(256) void head_kernel(const float* feat, const float* W,
                                                   const float* bias, float* fbuf)
{
  int i = blockIdx.x * 256 + threadIdx.x;  // 32*512
  int b = i >> 9, h = i & 511;
  const float* fr = feat + (size_t)b * 8192;
  const float* wr = W + (size_t)h * 8192;
  float a = bias[h];
  for (int k = 0; k < 8192; ++k) a += fr[k] * wr[k];
  fbuf[i] = tanhf(a);
}
__global__ void logits_kernel(const float* fbuf, const float* W, const float* bias, float* out)
{
  int b = blockIdx.x, tid = threadIdx.x;  // block 64
  __shared__ float lg[20];
  __shared__ float mred, lsred;
  if (tid < 20) {
    const float* fr = fbuf + b * 512;
    const float* wr = W + tid * 512;
    float a = bias[tid];
    for (int k = 0; k < 512; ++k) a += fr[k] * wr[k];
    lg[tid] = a;
  }
  __syncthreads();
  if (tid == 0) {
    float m = lg[0];
    for (int i = 1; i < 20; ++i) m = fmaxf(m, lg[i]);
    float ssum = 0;
    for (int i = 0; i < 20; ++i) ssum += expf(lg[i] - m);
    mred = m; lsred = logf(ssum);
  }
  __syncthreads();
  if (tid < 20) out[b * 20 + tid] = lg[tid] - mred - lsred;
}

// ---------------- host ----------------
extern "C" void kernel_launch(void* const* d_in, const int* in_sizes, int n_in,
                              void* d_out, int out_size, void* d_ws, size_t ws_size,
                              hipStream_t stream)
{
  const float* sentence = (const float*)d_in[0];
  const int* actions = (const int*)d_in[1];
  const float* token_empty = (const float*)d_in[2];
  const float* leaf_Wi = (const float*)d_in[3];
  const float* leaf_bi = (const float*)d_in[4];
  const float* leaf_Wo = (const float*)d_in[5];
  const float* leaf_bo = (const float*)d_in[6];
  const float* lstm_Wih = (const float*)d_in[7];
  const float* lstm_Whh = (const float*)d_in[8];
  const float* lstm_bih = (const float*)d_in[9];
  const float* lstm_bhh = (const float*)d_in[10];
  const float* stack_h0 = (const float*)d_in[11];
  const float* stack_c0 = (const float*)d_in[12];
  const float* act_emb = (const float*)d_in[13];
  const float* act_Wih = (const float*)d_in[14];
  const float* act_Whh = (const float*)d_in[15];
  const float* act_bih = (const float*)d_in[16];
  const float* act_bhh = (const float*)d_in[17];
  const float* act_h0 = (const float*)d_in[18];
  const float* act_c0 = (const float*)d_in[19];
  const float* red_W = (const float*)d_in[20];
  const float* red_b = (const float*)d_in[21];
  const float* h2f_W = (const float*)d_in[22];
  const float* h2f_b = (const float*)d_in[23];
  const float* f2a_W = (const float*)d_in[24];
  const float* f2a_b = (const float*)d_in[25];
  const float* att_W = (const float*)d_in[26];
  float* out = (float*)d_out;
  (void)in_sizes; (void)n_in; (void)out_size; (void)ws_size;

  char* ws = (char*)d_ws;
  size_t off = 0;
  auto alloc = [&](size_t bytes) -> void* {
    void* ptr = ws + off;
    off += (bytes + 255) & ~(size_t)255;
    return ptr;
  };
  __hip_bfloat16* sent_bf = (__hip_bfloat16*)alloc(16777216);   // [8192][1024] (b*256+t)
  __hip_bfloat16* hid_bf  = (__hip_bfloat16*)alloc(16777216);   // [8192][1024] (t*32+b)
  float* cell_f32 = (float*)alloc(33554432);                    // [8192][1024] (t*32+b)
  __hip_bfloat16* lWi_bf = (__hip_bfloat16*)alloc(2097152);
  __hip_bfloat16* lWo_bf = (__hip_bfloat16*)alloc(2097152);
  __hip_bfloat16* Whh_s = (__hip_bfloat16*)alloc(8388608);
  __hip_bfloat16* Wih_s = (__hip_bfloat16*)alloc(8388608);
  __hip_bfloat16* Whh_r = (__hip_bfloat16*)alloc(8388608);
  __hip_bfloat16* Wx_r  = (__hip_bfloat16*)alloc(8388608);
  __hip_bfloat16* Whh_a = (__hip_bfloat16*)alloc(8388608);
  __hip_bfloat16* xg_s = (__hip_bfloat16*)alloc(67108864);      // [8192][4096]
  __hip_bfloat16* xg_r = (__hip_bfloat16*)alloc(67108864);
  float* table = (float*)alloc(327680);
  float* sbias = (float*)alloc(16384);
  __hip_bfloat16* sb0 = (__hip_bfloat16*)alloc(65536);
  __hip_bfloat16* sb1 = (__hip_bfloat16*)alloc(65536);
  __hip_bfloat16* rb0 = (__hip_bfloat16*)alloc(65536);
  __hip_bfloat16* rb1 = (__hip_bfloat16*)alloc(65536);
  __hip_bfloat16* ab0 = (__hip_bfloat16*)alloc(65536);
  __hip_bfloat16* ab1 = (__hip_bfloat16*)alloc(65536);
  float* s1 = (float*)alloc(131072);
  float* s2 = (float*)alloc(131072);
  float* s3 = (float*)alloc(131072);
  float* atop = (float*)alloc(131072);
  unsigned int* flags = (unsigned int*)alloc(1024);
  float* qbuf = (float*)alloc(393216);
  float* attbuf = (float*)alloc(393216);
  float* feat = (float*)alloc(1048576);
  float* fbuf = (float*)alloc(65536);

  // conversions
  cast_kernel<<<32768, 256, 0, stream>>>(sent_bf, sentence, 8388608);
  cast_kernel<<<4096, 256, 0, stream>>>(lWi_bf, leaf_Wi, 1048576);
  cast_kernel<<<4096, 256, 0, stream>>>(lWo_bf, leaf_Wo, 1048576);
  cast_kernel<<<16384, 256, 0, stream>>>(Whh_s, lstm_Whh, 4194304);
  cast_kernel<<<16384, 256, 0, stream>>>(Wih_s, lstm_Wih, 4194304);
  cast_kernel<<<16384, 256, 0, stream>>>(Whh_a, act_Whh, 4194304);
  extract_half_kernel<<<16384, 256, 0, stream>>>(Whh_r, red_W, 4194304, 2048, 0);
  extract_half_kernel<<<16384, 256, 0, stream>>>(Wx_r, red_W, 4194304, 2048, 1024);
  bias_kernel<<<16, 256, 0, stream>>>(sbias, lstm_bih, lstm_bhh, 4096);
  act_table_kernel<<<320, 256, 0, stream>>>(act_emb, act_Wih, act_bih, act_bhh, table);

  // leaf module
  gemm_bt_kernel<<<dim3(64, 8), 256, 0, stream>>>(sent_bf, lWi_bf, cell_f32, nullptr,
                                                  leaf_bi, nullptr, 8192, 1024, 1024, 1, 0);
  gemm_bt_kernel<<<dim3(64, 8), 256, 0, stream>>>(sent_bf, lWo_bf, nullptr, hid_bf,
                                                  leaf_bo, cell_f32, 8192, 1024, 1024, 1, 2);

  // precomputed x-gates (bias folded)
  gemm_bt_kernel<<<dim3(64, 32), 256, 0, stream>>>(hid_bf, Wih_s, nullptr, xg_s,
                                                   sbias, nullptr, 8192, 4096, 1024, 0, 1);
  gemm_bt_kernel<<<dim3(64, 32), 256, 0, stream>>>(hid_bf, Wx_r, nullptr, xg_r,
                                                   red_b, nullptr, 8192, 4096, 1024, 0, 1);

  init_states_kernel<<<128, 256, 0, stream>>>(stack_h0, act_h0, sb0, ab0, flags);

  PP P;
  P.hid = hid_bf; P.cell = cell_f32;
  P.Whh_s = Whh_s; P.Wih_s = Wih_s; P.Whh_r = Whh_r; P.Whh_a = Whh_a;
  P.xg_s = xg_s; P.xg_r = xg_r;
  P.table = table; P.actions = actions;
  P.stack_c0 = stack_c0; P.act_c0 = act_c0; P.sbias = sbias;
  P.sb0 = sb0; P.sb1 = sb1; P.rb0 = rb0; P.rb1 = rb1; P.ab0 = ab0; P.ab1 = ab1;
  P.s1 = s1; P.s2 = s2; P.s3 = s3; P.atop = atop;
  P.flags = flags;
  scan_persist<<<192, 256, 0, stream>>>(P);

  // attention: s1, s2, s3
  att_q_kernel<<<dim3(4, 8, 3), 256, 0, stream>>>(s1, s2, s3, att_W, qbuf);
  att_sc_kernel<<<dim3(32, 3), 256, 0, stream>>>(qbuf, sentence, attbuf);

  // head
  feat_kernel<<<1024, 256, 0, stream>>>(s1, s2, s3, token_empty, atop, attbuf, feat);
  head_kernel<<<64, 256, 0, stream>>>(feat, h2f_W, h2f_b, fbuf);
  logits_kernel<<<32, 64, 0, stream>>>(fbuf, f2a_W, f2a_b, out);
}

// Round 5
// 3425.345 us; speedup vs baseline: 3.5862x; 1.0095x over previous
//
#include <hip/hip_runtime.h>
#include <hip/hip_bf16.h>
#include <math.h>

// B=32, T=256, D=1024, A=64, H=512, NA=20
#define DEV __device__ __forceinline__

typedef __bf16 bf16_t;
typedef bf16_t bf16x8 __attribute__((ext_vector_type(8)));
typedef float f32x4 __attribute__((ext_vector_type(4)));
typedef int i32x4 __attribute__((ext_vector_type(4)));

DEV void async16(const void* g, void* l) {
  __builtin_amdgcn_global_load_lds((const __attribute__((address_space(1))) void*)g,
                                   (__attribute__((address_space(3))) void*)l, 16, 0, 0);
}
DEV float sigmoidf_(float x) { return 1.f / (1.f + expf(-x)); }
DEV bf16x8 as_bf(i32x4 v) { union { i32x4 i; bf16x8 b; } u; u.i = v; return u.b; }

// ---- fine-grained device-coherent ops (bypass L1+L2, hit Infinity Cache) ----
DEV void flag_store(unsigned* p, unsigned v) {
  asm volatile("global_store_dword %0, %1, off sc0 sc1" :: "v"(p), "v"(v) : "memory");
}
DEV unsigned flag_load(const unsigned* p) {
  unsigned v;
  asm volatile("global_load_dword %0, %1, off sc0 sc1\ns_waitcnt vmcnt(0)"
               : "=v"(v) : "v"(p) : "memory");
  return v;
}
DEV void store16_sys(void* p, i32x4 v) {
  asm volatile("global_store_dwordx4 %0, %1, off sc0 sc1" :: "v"(p), "v"(v) : "memory");
}

#define WAITV(N) do { asm volatile("s_waitcnt vmcnt(" #N ")" ::: "memory"); \
                      __builtin_amdgcn_sched_barrier(0); } while (0)

template<int KB>
DEV void loads8(i32x4* dst, const __hip_bfloat16* arow) {
#pragma unroll
  for (int i = 0; i < 8; ++i)
    asm volatile("global_load_dwordx4 %0, %1, off offset:%2 sc0 sc1"
                 : "=v"(dst[i]) : "v"(arow), "i"((KB + i) * 64));
}
DEV void loads8rt(i32x4* dst, const __hip_bfloat16* arow, int kbase) {
#pragma unroll
  for (int i = 0; i < 8; ++i)
    asm volatile("global_load_dwordx4 %0, %1, off sc0 sc1"
                 : "=v"(dst[i]) : "v"(arow + (size_t)(kbase + i) * 32) : "memory");
}

template<int C>
DEV void ldsb8(bf16x8* b0, bf16x8* b1, const __hip_bfloat16* Wl,
               int sw, int kof, int r0, int r1) {
#pragma unroll
  for (int i = 0; i < 8; ++i) {
    const int kk = (C * 8 + i) * 32 + kof;
    b0[i] = *(const bf16x8*)&Wl[r0 * 1024 + (kk ^ sw)];
    b1[i] = *(const bf16x8*)&Wl[r1 * 1024 + (kk ^ sw)];
  }
}
DEV void mfma8x(const i32x4* a, const bf16x8* b0, const bf16x8* b1,
                f32x4& acc0, f32x4& acc1) {
#pragma unroll
  for (int i = 0; i < 8; ++i) {
    bf16x8 av = as_bf(a[i]);
    acc0 = __builtin_amdgcn_mfma_f32_16x16x32_bf16(av, b0[i], acc0, 0, 0, 0);
    acc1 = __builtin_amdgcn_mfma_f32_16x16x32_bf16(av, b1[i], acc1, 0, 0, 0);
  }
}

// K=1024 recurrent GEMM: A (h-state, bypass loads) x W (LDS-resident), 2-deep pipeline
DEV void mfma_step(const __hip_bfloat16* Ap, const __hip_bfloat16* Wl,
                   int mh, int nh, int l, f32x4& acc0, f32x4& acc1) {
  const __hip_bfloat16* arow = Ap + (mh * 16 + (l & 15)) * 1024 + (l >> 4) * 8;
  const int sw = (l & 7) << 3, kof = (l >> 4) * 8;
  const int r0 = nh * 32 + (l & 15), r1 = r0 + 16;
  i32x4 A0[8], A1[8];
  bf16x8 Ba0[8], Ba1[8], Bb0[8], Bb1[8];
  loads8<0>(A0, arow);
  loads8<8>(A1, arow);
  ldsb8<0>(Ba0, Ba1, Wl, sw, kof, r0, r1);
  WAITV(8);
  mfma8x(A0, Ba0, Ba1, acc0, acc1);
  loads8<16>(A0, arow);
  ldsb8<1>(Bb0, Bb1, Wl, sw, kof, r0, r1);
  WAITV(8);
  mfma8x(A1, Bb0, Bb1, acc0, acc1);
  loads8<24>(A1, arow);
  ldsb8<2>(Ba0, Ba1, Wl, sw, kof, r0, r1);
  WAITV(8);
  mfma8x(A0, Ba0, Ba1, acc0, acc1);
  ldsb8<3>(Bb0, Bb1, Wl, sw, kof, r0, r1);
  WAITV(0);
  mfma8x(A1, Bb0, Bb1, acc0, acc1);
}

// final-phase pass: A bypass loads, W from global (cached)
DEV void mfma_pass_glb(const __hip_bfloat16* Ap, const __hip_bfloat16* __restrict__ Wg,
                       int d0, int mh, int nh, int l, f32x4& acc0, f32x4& acc1) {
  const __hip_bfloat16* arow = Ap + (mh * 16 + (l & 15)) * 1024 + (l >> 4) * 8;
  const size_t g0 = ((size_t)(2 * nh) * 1024 + d0 + (l & 15)) * 1024;
  const size_t g1 = g0 + 1048576;
  const int kof = (l >> 4) * 8;
  i32x4 A[8];
  for (int c = 0; c < 4; ++c) {
    loads8rt(A, arow, c * 8);
    WAITV(0);
#pragma unroll
    for (int i = 0; i < 8; ++i) {
      const int kk = (c * 8 + i) * 32 + kof;
      bf16x8 b0 = *(const bf16x8*)&Wg[g0 + kk];
      bf16x8 b1 = *(const bf16x8*)&Wg[g1 + kk];
      bf16x8 av = as_bf(A[i]);
      acc0 = __builtin_amdgcn_mfma_f32_16x16x32_bf16(av, b0, acc0, 0, 0, 0);
      acc1 = __builtin_amdgcn_mfma_f32_16x16x32_bf16(av, b1, acc1, 0, 0, 0);
    }
  }
}

// ---------------- generic bf16 MFMA GEMM: C[M,N] = A[M,K] @ Bw[N,K]^T + bias ----------------
__global__ __launch_bounds__(256) void gemm_bt_kernel(
    const __hip_bfloat16* __restrict__ A, const __hip_bfloat16* __restrict__ Bw,
    float* __restrict__ outF, __hip_bfloat16* __restrict__ outBF,
    const float* __restrict__ bias, const float* __restrict__ aux,
    int M, int N, int K, int remap, int mode)
{
  __shared__ __hip_bfloat16 As[128 * 64];
  __shared__ __hip_bfloat16 Bs[128 * 64];
  const int tid = threadIdx.x;
  const int w = tid >> 6, l = tid & 63;
  const int m0 = blockIdx.x * 128, n0 = blockIdx.y * 128;
  const int wm = (w >> 1) * 64, wn = (w & 1) * 64;
  const int row_s = tid >> 3, kc = tid & 7;
  f32x4 acc[4][4] = {};
  for (int k0 = 0; k0 < K; k0 += 64) {
    const __hip_bfloat16* ga = A + (size_t)(m0 + row_s) * K + k0 + kc * 8;
    const __hip_bfloat16* gb = Bw + (size_t)(n0 + row_s) * K + k0 + kc * 8;
    __hip_bfloat16* la = As + w * 512;
    __hip_bfloat16* lb = Bs + w * 512;
#pragma unroll
    for (int p = 0; p < 4; ++p) {
      async16(ga + (size_t)p * 32 * K, la + p * 2048);
      async16(gb + (size_t)p * 32 * K, lb + p * 2048);
    }
    __syncthreads();
#pragma unroll
    for (int kb = 0; kb < 2; ++kb) {
      bf16x8 af[4], bfr[4];
#pragma unroll
      for (int i = 0; i < 4; ++i)
        af[i] = *(const bf16x8*)&As[(wm + i * 16 + (l & 15)) * 64 + kb * 32 + (l >> 4) * 8];
#pragma unroll
      for (int j = 0; j < 4; ++j)
        bfr[j] = *(const bf16x8*)&Bs[(wn + j * 16 + (l & 15)) * 64 + kb * 32 + (l >> 4) * 8];
#pragma unroll
      for (int i = 0; i < 4; ++i)
#pragma unroll
        for (int j = 0; j < 4; ++j)
          acc[i][j] = __builtin_amdgcn_mfma_f32_16x16x32_bf16(af[i], bfr[j], acc[i][j], 0, 0, 0);
    }
    __syncthreads();
  }
#pragma unroll
  for (int i = 0; i < 4; ++i) {
#pragma unroll
    for (int j = 0; j < 4; ++j) {
      const int ncol = n0 + wn + j * 16 + (l & 15);
      const float bv = bias ? bias[ncol] : 0.f;
#pragma unroll
      for (int r = 0; r < 4; ++r) {
        int m = m0 + wm + i * 16 + (l >> 4) * 4 + r;
        int row = remap ? (((m & 255) << 5) | (m >> 8)) : m;
        float v = acc[i][j][r] + bv;
        if (mode == 0) {
          outF[(size_t)row * N + ncol] = v;
        } else if (mode == 1) {
          outBF[(size_t)row * N + ncol] = __float2bfloat16(v);
        } else {
          float cv = aux[(size_t)row * N + ncol];
          outBF[(size_t)row * N + ncol] = __float2bfloat16(sigmoidf_(v) * tanhf(cv));
        }
      }
    }
  }
}

// ---------------- persistent scan ----------------
struct PP {
  const __hip_bfloat16* hid;     // [8192][1024]  rows t*32+b
  const float* cell;             // [8192][1024]  rows t*32+b
  const __hip_bfloat16 *Whh_s, *Wih_s, *Whh_r, *Whh_a;  // [4096][1024]
  const __hip_bfloat16 *xg_s, *xg_r;                    // [8192][4096] bias folded
  const float* table;            // [20][4096]
  const int* actions;            // [32][256]
  const float *stack_c0, *act_c0, *sbias;
  __hip_bfloat16 *sb0, *sb1, *rb0, *rb1, *ab0, *ab1;    // h dbuf [32][1024] bf16
  float *s1, *s2, *s3, *atop;    // [32][1024] f32
  unsigned int* flags;           // [3*64]
};

__global__ __launch_bounds__(256, 1) void scan_persist(PP P)
{
  __shared__ __hip_bfloat16 Wl[64 * 1024];             // 128 KB, XOR-swizzled
  __shared__ float gsm[32][16][4];                     // 8 KB gate exchange
  __shared__ __align__(16) __hip_bfloat16 hstage[32][16];  // 1 KB packed h staging
  const int bid = blockIdx.x;
  const int scan = bid >> 6;                 // 0 stack, 1 reduce, 2 action
  const int slot = bid & 63;
  const int d0 = slot * 16;
  const int tid = threadIdx.x;
  const int l = tid & 63, w = tid >> 6;
  const int mh = w >> 1, nh = w & 1;

  const __hip_bfloat16* Wg = (scan == 0) ? P.Whh_s : ((scan == 1) ? P.Whh_r : P.Whh_a);
  // stage W slice: local row r <- global row (r>>4)*1024 + d0 + (r&15); swizzle k ^= (r&7)<<3
  for (int idx = tid; idx < 64 * 128; idx += 256) {
    int r = idx >> 7, k = (idx & 127) * 8;
    int grow = ((r >> 4) << 10) + d0 + (r & 15);
    bf16x8 v = *(const bf16x8*)&Wg[(size_t)grow * 1024 + k];
    *(bf16x8*)&Wl[r * 1024 + (k ^ ((r & 7) << 3))] = v;
  }
  // persistent cell state in registers: thread owns (b,dd) pairs e and e+256
  const int e0 = tid, e1 = tid + 256;
  const int b0_ = e0 >> 4, dd0 = e0 & 15, b1_ = e1 >> 4, dd1 = e1 & 15;
  float creg0, creg1;
  if (scan == 0)      { creg0 = P.stack_c0[d0 + dd0]; creg1 = P.stack_c0[d0 + dd1]; }
  else if (scan == 1) { creg0 = P.cell[b0_ * 1024 + d0 + dd0]; creg1 = P.cell[b1_ * 1024 + d0 + dd1]; }
  else                { creg0 = P.act_c0[d0 + dd0]; creg1 = P.act_c0[d0 + dd1]; }
  __syncthreads();

  __hip_bfloat16 *bufA, *bufB;
  if (scan == 0)      { bufA = P.sb0; bufB = P.sb1; }
  else if (scan == 1) { bufA = P.rb0; bufB = P.rb1; }
  else                { bufA = P.ab0; bufB = P.ab1; }
  unsigned int* Fb = P.flags + scan * 64;
  const int Ns = (scan == 1) ? 255 : 256;
  const int mbase = mh * 16 + (l >> 4) * 4;

  for (int s = 0; s < Ns; ++s) {
    const __hip_bfloat16* Ap = (s & 1) ? bufB : bufA;
    if (scan == 1 && s == 0) Ap = P.hid;           // hid_t[0]
    __hip_bfloat16* Hout = (s & 1) ? bufA : bufB;
    f32x4 acc0 = {}, acc1 = {};
    mfma_step(Ap, Wl, mh, nh, l, acc0, acc1);
#pragma unroll
    for (int r = 0; r < 4; ++r) {
      gsm[mbase + r][l & 15][nh * 2 + 0] = acc0[r];
      gsm[mbase + r][l & 15][nh * 2 + 1] = acc1[r];
    }
    __syncthreads();
#pragma unroll
    for (int q = 0; q < 2; ++q) {
      const int b = q ? b1_ : b0_, dd = q ? dd1 : dd0;
      const int d = d0 + dd;
      float& creg = q ? creg1 : creg0;
      float g0 = gsm[b][dd][0], g1 = gsm[b][dd][1], g2 = gsm[b][dd][2], g3 = gsm[b][dd][3];
      if (scan == 1) {
        const __hip_bfloat16* xr = P.xg_r + ((size_t)(s + 1) * 32 + b) * 4096;
        float ig = sigmoidf_(g0 + __bfloat162float(xr[d]));
        float lg = sigmoidf_(g1 + __bfloat162float(xr[1024 + d]));
        float rg = sigmoidf_(g2 + __bfloat162float(xr[2048 + d]));
        float cand = tanhf(g3 + __bfloat162float(xr[3072 + d]));
        float rcv = P.cell[((size_t)(s + 1) * 32 + b) * 1024 + d];
        float c2 = ig * cand + lg * creg + rg * rcv;
        creg = c2;
        hstage[b][dd] = __float2bfloat16(tanhf(c2));
      } else {
        float bi0, bi1, bi2, bi3;
        if (scan == 0) {
          const __hip_bfloat16* xr = P.xg_s + ((size_t)s * 32 + b) * 4096;
          bi0 = __bfloat162float(xr[d]);        bi1 = __bfloat162float(xr[1024 + d]);
          bi2 = __bfloat162float(xr[2048 + d]); bi3 = __bfloat162float(xr[3072 + d]);
        } else {
          int a = P.actions[b * 256 + s];
          const float* tb = P.table + a * 4096;
          bi0 = tb[d]; bi1 = tb[1024 + d]; bi2 = tb[2048 + d]; bi3 = tb[3072 + d];
        }
        float c2 = sigmoidf_(g1 + bi1) * creg + sigmoidf_(g0 + bi0) * tanhf(g2 + bi2);
        float h2 = sigmoidf_(g3 + bi3) * tanhf(c2);
        creg = c2;
        hstage[b][dd] = __float2bfloat16(h2);
        if (scan == 0 && s == 254) P.s3[b * 1024 + d] = h2;
        if (scan == 0 && s == 255) P.s2[b * 1024 + d] = h2;
        if (scan == 2 && s == 255) P.atop[b * 1024 + d] = h2;
      }
    }
    __syncthreads();
    // ---- packed 16B device-coherent h stores (wave 0 only) ----
    if (tid < 64) {
      const int bb = tid >> 1, hf = tid & 1;
      union { bf16x8 b8; i32x4 i4; } u;
      u.b8 = *(const bf16x8*)&hstage[bb][hf * 8];
      store16_sys(Hout + bb * 1024 + d0 + hf * 8, u.i4);
    }
    asm volatile("s_waitcnt vmcnt(0)" ::: "memory");
    __syncthreads();
    if (tid == 0) flag_store(Fb + slot, (unsigned)(s + 1));
    if (tid < 64) {
      const unsigned tgt = (unsigned)(s + 1);
      while (flag_load(Fb + tid) < tgt) __builtin_amdgcn_s_sleep(2);
    }
    __syncthreads();
  }

  if (scan == 0) {
    // wait for reduce scan, then s1 = lstm_cell(red_h, hf, cf)
    if (tid < 64) {
      while (flag_load(P.flags + 64 + tid) < 255u) __builtin_amdgcn_s_sleep(2);
    }
    __syncthreads();
    f32x4 acc0 = {}, acc1 = {};
    mfma_step(P.sb0, Wl, mh, nh, l, acc0, acc1);              // hf @ Whh^T (bypass A)
    mfma_pass_glb(P.rb1, P.Wih_s, d0, mh, nh, l, acc0, acc1); // red_h @ Wih^T
#pragma unroll
    for (int r = 0; r < 4; ++r) {
      gsm[mbase + r][l & 15][nh * 2 + 0] = acc0[r];
      gsm[mbase + r][l & 15][nh * 2 + 1] = acc1[r];
    }
    __syncthreads();
#pragma unroll
    for (int q = 0; q < 2; ++q) {
      const int b = q ? b1_ : b0_, dd = q ? dd1 : dd0;
      const int d = d0 + dd;
      float creg = q ? creg1 : creg0;   // cf
      float g0 = gsm[b][dd][0], g1 = gsm[b][dd][1], g2 = gsm[b][dd][2], g3 = gsm[b][dd][3];
      float bi0 = P.sbias[d], bi1 = P.sbias[1024 + d], bi2 = P.sbias[2048 + d], bi3 = P.sbias[3072 + d];
      float c2 = sigmoidf_(g1 + bi1) * creg + sigmoidf_(g0 + bi0) * tanhf(g2 + bi2);
      float h2 = sigmoidf_(g3 + bi3) * tanhf(c2);
      P.s1[b * 1024 + d] = h2;
    }
  }
}

// ---------------- small utility kernels ----------------
__global__ void cast_kernel(__hip_bfloat16* dst, const float* src, int n) {
  int i = blockIdx.x * 256 + threadIdx.x;
  if (i < n) dst[i] = __float2bfloat16(src[i]);
}
__global__ void extract_half_kernel(__hip_bfloat16* dst, const float* src, int n,
                                    int src_stride, int src_off) {
  int i = blockIdx.x * 256 + threadIdx.x;   // n = 4096*1024
  if (i < n) {
    int r = i >> 10, k = i & 1023;
    dst[i] = __float2bfloat16(src[(size_t)r * src_stride + src_off + k]);
  }
}
__global__ void bias_kernel(float* dst, const float* a, const float* b, int n) {
  int i = blockIdx.x * 256 + threadIdx.x;
  if (i < n) dst[i] = a[i] + b[i];
}
__global__ void act_table_kernel(const float* emb, const float* Wih, const float* bih,
                                 const float* bhh, float* table) {
  int i = blockIdx.x * 256 + threadIdx.x;  // 20*4096
  int a = i >> 12, n = i & 4095;
  float acc = bih[n] + bhh[n];
  const float* er = emb + a * 64;
  const float* wr = Wih + (size_t)n * 64;
  for (int k = 0; k < 64; ++k) acc += er[k] * wr[k];
  table[i] = acc;
}
__global__ void init_states_kernel(const float* stack_h0, const float* act_h0,
                                   __hip_bfloat16* sb0, __hip_bfloat16* ab0,
                                   unsigned int* flags)
{
  int i = blockIdx.x * 256 + threadIdx.x;  // 32768
  int d = i & 1023;
  sb0[i] = __float2bfloat16(stack_h0[d]);
  ab0[i] = __float2bfloat16(act_h0[d]);
  if (i < 192) flags[i] = 0u;
}

// ---------------- attention ----------------
__global__ __launch_bounds__(256) void att_q_kernel(
    const float* s1, const float* s2, const float* s3, const float* attW, float* q)
{
  int eb = blockIdx.x, bg = blockIdx.y, j = blockIdx.z;
  const float* sj = (j == 0) ? s1 : ((j == 1) ? s2 : s3);
  __shared__ float ls[4][1024];
  int tid = threadIdx.x;
  for (int i = tid; i < 4096; i += 256)
    ls[i >> 10][i & 1023] = sj[(size_t)(bg * 4 + (i >> 10)) * 1024 + (i & 1023)];
  __syncthreads();
  int e = eb * 256 + tid;
  const float* Wj = attW + (size_t)j * 1024 * 1024;
  float a0 = 0, a1 = 0, a2 = 0, a3 = 0;
  for (int d = 0; d < 1024; ++d) {
    float wv = Wj[(size_t)d * 1024 + e];
    a0 += ls[0][d] * wv; a1 += ls[1][d] * wv; a2 += ls[2][d] * wv; a3 += ls[3][d] * wv;
  }
  q[((size_t)j * 32 + bg * 4 + 0) * 1024 + e] = a0;
  q[((size_t)j * 32 + bg * 4 + 1) * 1024 + e] = a1;
  q[((size_t)j * 32 + bg * 4 + 2) * 1024 + e] = a2;
  q[((size_t)j * 32 + bg * 4 + 3) * 1024 + e] = a3;
}

__global__ __launch_bounds__(256) void att_sc_kernel(const float* q, const float* sent, float* att)
{
  int b = blockIdx.x, j = blockIdx.y;
  __shared__ float qs[1024];
  __shared__ float wsm[256];
  __shared__ float red[8];
  int tid = threadIdx.x, w = tid >> 6, l = tid & 63;
  for (int i = tid; i < 1024; i += 256) qs[i] = q[((size_t)j * 32 + b) * 1024 + i];
  __syncthreads();
  const float* sp = sent + ((size_t)b * 256 + tid) * 1024;
  float dot = 0;
  for (int k = 0; k < 1024; ++k) dot += qs[k] * sp[k];
  float v = dot;
  for (int off = 32; off; off >>= 1) v = fmaxf(v, __shfl_xor(v, off));
  if (l == 0) red[w] = v;
  __syncthreads();
  float m = fmaxf(fmaxf(red[0], red[1]), fmaxf(red[2], red[3]));
  float ex = expf(dot - m);
  float sv = ex;
  for (int off = 32; off; off >>= 1) sv += __shfl_xor(sv, off);
  if (l == 0) red[4 + w] = sv;
  __syncthreads();
  float ssum = red[4] + red[5] + red[6] + red[7];
  wsm[tid] = ex / ssum;
  __syncthreads();
  for (int it = 0; it < 4; ++it) {
    int e = it * 256 + tid;
    float a = 0;
    for (int t2 = 0; t2 < 256; ++t2) a += wsm[t2] * sent[((size_t)b * 256 + t2) * 1024 + e];
    att[((size_t)j * 32 + b) * 1024 + e] = a;
  }
}

// ---------------- head ----------------
__global__ void feat_kernel(const float* s1, const float* s2, const float* s3,
                            const float* tok, const float* atop, const float* att, float* feat)
{
  int i = blockIdx.x * 256 + threadIdx.x;  // 32*8192
  int b = i >> 13, jj = (i >> 10) & 7, d = i & 1023;
  int sidx = b * 1024 + d;
  float v;
  switch (jj) {
    case 0: v = s1[sidx]; break;
    case 1: v = s2[sidx]; break;
    case 2: v = s3[sidx]; break;
    case 3: v = tok[d]; break;
    case 4: v = atop[sidx]; break;
    default: v = att[((size_t)(jj - 5) * 32 + b) * 1024 + d];
  }
  feat[i] = v;
}
__global__ __launch_bounds__(256) void head_kernel(const float* feat, const float* W,
                                                   const float* bias, float* fbuf)
{
  int i = blockIdx.x * 256 + threadIdx.x;  // 32*512
  int b = i >> 9, h = i & 511;
  const float* fr = feat + (size_t)b * 8192;
  const float* wr = W + (size_t)h * 8192;
  float a = bias[h];
  for (int k = 0; k < 8192; ++k) a += fr[k] * wr[k];
  fbuf[i] = tanhf(a);
}
__global__ void logits_kernel(const float* fbuf, const float* W, const float* bias, float* out)
{
  int b = blockIdx.x, tid = threadIdx.x;  // block 64
  __shared__ float lg[20];
  __shared__ float mred, lsred;
  if (tid < 20) {
    const float* fr = fbuf + b * 512;
    const float* wr = W + tid * 512;
    float a = bias[tid];
    for (int k = 0; k < 512; ++k) a += fr[k] * wr[k];
    lg[tid] = a;
  }
  __syncthreads();
  if (tid == 0) {
    float m = lg[0];
    for (int i = 1; i < 20; ++i) m = fmaxf(m, lg[i]);
    float ssum = 0;
    for (int i = 0; i < 20; ++i) ssum += expf(lg[i] - m);
    mred = m; lsred = logf(ssum);
  }
  __syncthreads();
  if (tid < 20) out[b * 20 + tid] = lg[tid] - mred - lsred;
}

// ---------------- host ----------------
extern "C" void kernel_launch(void* const* d_in, const int* in_sizes, int n_in,
                              void* d_out, int out_size, void* d_ws, size_t ws_size,
                              hipStream_t stream)
{
  const float* sentence = (const float*)d_in[0];
  const int* actions = (const int*)d_in[1];
  const float* token_empty = (const float*)d_in[2];
  const float* leaf_Wi = (const float*)d_in[3];
  const float* leaf_bi = (const float*)d_in[4];
  const float* leaf_Wo = (const float*)d_in[5];
  const float* leaf_bo = (const float*)d_in[6];
  const float* lstm_Wih = (const float*)d_in[7];
  const float* lstm_Whh = (const float*)d_in[8];
  const float* lstm_bih = (const float*)d_in[9];
  const float* lstm_bhh = (const float*)d_in[10];
  const float* stack_h0 = (const float*)d_in[11];
  const float* stack_c0 = (const float*)d_in[12];
  const float* act_emb = (const float*)d_in[13];
  const float* act_Wih = (const float*)d_in[14];
  const float* act_Whh = (const float*)d_in[15];
  const float* act_bih = (const float*)d_in[16];
  const float* act_bhh = (const float*)d_in[17];
  const float* act_h0 = (const float*)d_in[18];
  const float* act_c0 = (const float*)d_in[19];
  const float* red_W = (const float*)d_in[20];
  const float* red_b = (const float*)d_in[21];
  const float* h2f_W = (const float*)d_in[22];
  const float* h2f_b = (const float*)d_in[23];
  const float* f2a_W = (const float*)d_in[24];
  const float* f2a_b = (const float*)d_in[25];
  const float* att_W = (const float*)d_in[26];
  float* out = (float*)d_out;
  (void)in_sizes; (void)n_in; (void)out_size; (void)ws_size;

  char* ws = (char*)d_ws;
  size_t off = 0;
  auto alloc = [&](size_t bytes) -> void* {
    void* ptr = ws + off;
    off += (bytes + 255) & ~(size_t)255;
    return ptr;
  };
  __hip_bfloat16* sent_bf = (__hip_bfloat16*)alloc(16777216);   // [8192][1024] (b*256+t)
  __hip_bfloat16* hid_bf  = (__hip_bfloat16*)alloc(16777216);   // [8192][1024] (t*32+b)
  float* cell_f32 = (float*)alloc(33554432);                    // [8192][1024] (t*32+b)
  __hip_bfloat16* lWi_bf = (__hip_bfloat16*)alloc(2097152);
  __hip_bfloat16* lWo_bf = (__hip_bfloat16*)alloc(2097152);
  __hip_bfloat16* Whh_s = (__hip_bfloat16*)alloc(8388608);
  __hip_bfloat16* Wih_s = (__hip_bfloat16*)alloc(8388608);
  __hip_bfloat16* Whh_r = (__hip_bfloat16*)alloc(8388608);
  __hip_bfloat16* Wx_r  = (__hip_bfloat16*)alloc(8388608);
  __hip_bfloat16* Whh_a = (__hip_bfloat16*)alloc(8388608);
  __hip_bfloat16* xg_s = (__hip_bfloat16*)alloc(67108864);      // [8192][4096]
  __hip_bfloat16* xg_r = (__hip_bfloat16*)alloc(67108864);
  float* table = (float*)alloc(327680);
  float* sbias = (float*)alloc(16384);
  __hip_bfloat16* sb0 = (__hip_bfloat16*)alloc(65536);
  __hip_bfloat16* sb1 = (__hip_bfloat16*)alloc(65536);
  __hip_bfloat16* rb0 = (__hip_bfloat16*)alloc(65536);
  __hip_bfloat16* rb1 = (__hip_bfloat16*)alloc(65536);
  __hip_bfloat16* ab0 = (__hip_bfloat16*)alloc(65536);
  __hip_bfloat16* ab1 = (__hip_bfloat16*)alloc(65536);
  float* s1 = (float*)alloc(131072);
  float* s2 = (float*)alloc(131072);
  float* s3 = (float*)alloc(131072);
  float* atop = (float*)alloc(131072);
  unsigned int* flags = (unsigned int*)alloc(1024);
  float* qbuf = (float*)alloc(393216);
  float* attbuf = (float*)alloc(393216);
  float* feat = (float*)alloc(1048576);
  float* fbuf = (float*)alloc(65536);

  // conversions
  cast_kernel<<<32768, 256, 0, stream>>>(sent_bf, sentence, 8388608);
  cast_kernel<<<4096, 256, 0, stream>>>(lWi_bf, leaf_Wi, 1048576);
  cast_kernel<<<4096, 256, 0, stream>>>(lWo_bf, leaf_Wo, 1048576);
  cast_kernel<<<16384, 256, 0, stream>>>(Whh_s, lstm_Whh, 4194304);
  cast_kernel<<<16384, 256, 0, stream>>>(Wih_s, lstm_Wih, 4194304);
  cast_kernel<<<16384, 256, 0, stream>>>(Whh_a, act_Whh, 4194304);
  extract_half_kernel<<<16384, 256, 0, stream>>>(Whh_r, red_W, 4194304, 2048, 0);
  extract_half_kernel<<<16384, 256, 0, stream>>>(Wx_r, red_W, 4194304, 2048, 1024);
  bias_kernel<<<16, 256, 0, stream>>>(sbias, lstm_bih, lstm_bhh, 4096);
  act_table_kernel<<<320, 256, 0, stream>>>(act_emb, act_Wih, act_bih, act_bhh, table);

  // leaf module
  gemm_bt_kernel<<<dim3(64, 8), 256, 0, stream>>>(sent_bf, lWi_bf, cell_f32, nullptr,
                                                  leaf_bi, nullptr, 8192, 1024, 1024, 1, 0);
  gemm_bt_kernel<<<dim3(64, 8), 256, 0, stream>>>(sent_bf, lWo_bf, nullptr, hid_bf,
                                                  leaf_bo, cell_f32, 8192, 1024, 1024, 1, 2);

  // precomputed x-gates (bias folded)
  gemm_bt_kernel<<<dim3(64, 32), 256, 0, stream>>>(hid_bf, Wih_s, nullptr, xg_s,
                                                   sbias, nullptr, 8192, 4096, 1024, 0, 1);
  gemm_bt_kernel<<<dim3(64, 32), 256, 0, stream>>>(hid_bf, Wx_r, nullptr, xg_r,
                                                   red_b, nullptr, 8192, 4096, 1024, 0, 1);

  init_states_kernel<<<128, 256, 0, stream>>>(stack_h0, act_h0, sb0, ab0, flags);

  PP P;
  P.hid = hid_bf; P.cell = cell_f32;
  P.Whh_s = Whh_s; P.Wih_s = Wih_s; P.Whh_r = Whh_r; P.Whh_a = Whh_a;
  P.xg_s = xg_s; P.xg_r = xg_r;
  P.table = table; P.actions = actions;
  P.stack_c0 = stack_c0; P.act_c0 = act_c0; P.sbias = sbias;
  P.sb0 = sb0; P.sb1 = sb1; P.rb0 = rb0; P.rb1 = rb1; P.ab0 = ab0; P.ab1 = ab1;
  P.s1 = s1; P.s2 = s2; P.s3 = s3; P.atop = atop;
  P.flags = flags;
  scan_persist<<<192, 256, 0, stream>>>(P);

  // attention: s1, s2, s3
  att_q_kernel<<<dim3(4, 8, 3), 256, 0, stream>>>(s1, s2, s3, att_W, qbuf);
  att_sc_kernel<<<dim3(32, 3), 256, 0, stream>>>(qbuf, sentence, attbuf);

  // head
  feat_kernel<<<1024, 256, 0, stream>>>(s1, s2, s3, token_empty, atop, attbuf, feat);
  head_kernel<<<64, 256, 0, stream>>>(feat, h2f_W, h2f_b, fbuf);
  logits_kernel<<<32, 64, 0, stream>>>(fbuf, f2a_W, f2a_b, out);
}